// Round 1
// baseline (1085.571 us; speedup 1.0000x reference)
//
#include <hip/hip_runtime.h>

#define D 128
#define EPSBN 1e-5f

// ---------------- setup kernels ----------------

__global__ void k_deg(const int* __restrict__ ei, int E, int* __restrict__ deg) {
    int e = blockIdx.x * 256 + threadIdx.x;
    if (e < E) atomicAdd(&deg[ei[E + e]], 1);
}

__global__ void k_dinv(const int* __restrict__ deg, float* __restrict__ dinv, int N) {
    int v = blockIdx.x * 256 + threadIdx.x;
    if (v < N) {
        int d = deg[v];
        dinv[v] = (d > 0) ? rsqrtf((float)d) : 0.0f;
    }
}

// single-block Hillis-Steele scan over N counts -> row_ptr (exclusive), cursor copy
__global__ void k_scan(const int* __restrict__ cnt, int* __restrict__ row_ptr,
                       int* __restrict__ cursor, int N) {
    __shared__ int sm[1024];
    __shared__ int sbase;
    int tid = threadIdx.x;
    if (tid == 0) sbase = 0;
    __syncthreads();
    for (int start = 0; start < N; start += 1024) {
        int i = start + tid;
        int v = (i < N) ? cnt[i] : 0;
        sm[tid] = v;
        __syncthreads();
        for (int off = 1; off < 1024; off <<= 1) {
            int t = (tid >= off) ? sm[tid - off] : 0;
            __syncthreads();
            sm[tid] += t;
            __syncthreads();
        }
        int excl = sbase + sm[tid] - v;
        if (i < N) { row_ptr[i] = excl; cursor[i] = excl; }
        __syncthreads();
        if (tid == 0) sbase += sm[1023];
        __syncthreads();
    }
    if (tid == 0) row_ptr[N] = sbase;
}

// fill CSR (grouped by col) + accumulate c[v][k] = sum norm*attr[e][k]
__global__ void k_fill(const int* __restrict__ ei, const float* __restrict__ attr,
                       const float* __restrict__ dinv, int* __restrict__ cursor,
                       int* __restrict__ csr_src, float* __restrict__ csr_w,
                       float* __restrict__ cvals, int E) {
    int e = blockIdx.x * 256 + threadIdx.x;
    if (e >= E) return;
    int r = ei[e], c = ei[E + e];
    float nm = dinv[r] * dinv[c];
    int pos = atomicAdd(&cursor[c], 1);
    csr_src[pos] = r;
    csr_w[pos] = nm;
#pragma unroll
    for (int k = 0; k < 4; ++k)
        atomicAdd(&cvals[c * 4 + k], nm * attr[e * 4 + k]);
}

// ---------------- per-layer kernels ----------------

// agg[v][d] = sum_j w_j * h_in[src_j][d] + sum_k c[v][k]*Wcat[k][d]
__global__ __launch_bounds__(128) void k_spmm(
        const float* __restrict__ h_in, const int* __restrict__ row_ptr,
        const int* __restrict__ csr_src, const float* __restrict__ csr_w,
        const float* __restrict__ cvals,
        const float* __restrict__ W1l, const float* __restrict__ W2l,
        float* __restrict__ agg, int N) {
    int v = blockIdx.x;
    int d = threadIdx.x;  // 0..127
    float c0 = cvals[v * 4 + 0], c1 = cvals[v * 4 + 1];
    float c2 = cvals[v * 4 + 2], c3 = cvals[v * 4 + 3];
    float acc = c0 * W1l[d] + c1 * W1l[D + d] + c2 * W1l[2 * D + d] + c3 * W2l[d];
    int jb = row_ptr[v], je = row_ptr[v + 1];
    for (int j = jb; j < je; ++j) {
        acc += csr_w[j] * h_in[(size_t)csr_src[j] * D + d];
    }
    agg[(size_t)v * D + d] = acc;
}

// h2 = relu([h_in, agg] @ Wm^T + bm)   Wm: [D][2D] row-major
#define TN 64
#define BK 32
__global__ __launch_bounds__(256) void k_gemm(
        const float* __restrict__ h_in, const float* __restrict__ agg,
        const float* __restrict__ Wml, const float* __restrict__ bml,
        float* __restrict__ h2, int N) {
    __shared__ float As[TN][BK + 1];    // 64 x 33 (pad: conflict-free scalar a-reads)
    __shared__ float Bs[BK][D + 4];     // 32 x 132 (pad keeps 16B align for b128 reads)
    int tid = threadIdx.x;
    int n0 = blockIdx.x * TN;
    int tx = tid & 15, ty = tid >> 4;
    int cx = tx * 8, ry = ty * 4;
    float acc[4][8];
#pragma unroll
    for (int i = 0; i < 4; i++)
#pragma unroll
        for (int j = 0; j < 8; j++) acc[i][j] = 0.f;

    for (int kc = 0; kc < 8; ++kc) {
        int k0 = kc * BK;
        const float* src = (k0 < D) ? (h_in + (size_t)n0 * D + k0)
                                    : (agg + (size_t)n0 * D + (k0 - D));
        // A chunk: 64x32, 2 float4 per thread
#pragma unroll
        for (int i = 0; i < 2; ++i) {
            int id = tid + i * 256;          // 0..511
            int r = id >> 3;                 // 0..63
            int kk = (id & 7) * 4;
            float4 val = make_float4(0.f, 0.f, 0.f, 0.f);
            if (n0 + r < N) val = *(const float4*)(src + (size_t)r * D + kk);
            As[r][kk + 0] = val.x; As[r][kk + 1] = val.y;
            As[r][kk + 2] = val.z; As[r][kk + 3] = val.w;
        }
        // B chunk: Bs[kk][d] = Wm[d][k0+kk], 128x32, 4 float4 per thread
#pragma unroll
        for (int i = 0; i < 4; ++i) {
            int f4 = tid + i * 256;          // 0..1023
            int d = f4 >> 3;                 // 0..127
            int kkb = (f4 & 7) * 4;
            float4 w = *(const float4*)(Wml + (size_t)d * 256 + k0 + kkb);
            Bs[kkb + 0][d] = w.x; Bs[kkb + 1][d] = w.y;
            Bs[kkb + 2][d] = w.z; Bs[kkb + 3][d] = w.w;
        }
        __syncthreads();
#pragma unroll
        for (int kk = 0; kk < BK; ++kk) {
            float4 b0 = *(const float4*)&Bs[kk][cx];
            float4 b1 = *(const float4*)&Bs[kk][cx + 4];
            float bv[8] = {b0.x, b0.y, b0.z, b0.w, b1.x, b1.y, b1.z, b1.w};
            float av[4] = {As[ry + 0][kk], As[ry + 1][kk], As[ry + 2][kk], As[ry + 3][kk]};
#pragma unroll
            for (int i = 0; i < 4; i++)
#pragma unroll
                for (int j = 0; j < 8; j++)
                    acc[i][j] += av[i] * bv[j];
        }
        __syncthreads();
    }
    float bias[8];
#pragma unroll
    for (int j = 0; j < 8; j++) bias[j] = bml[cx + j];
#pragma unroll
    for (int i = 0; i < 4; i++) {
        int r = n0 + ry + i;
        if (r < N) {
            float4 o0, o1;
            o0.x = fmaxf(acc[i][0] + bias[0], 0.f);
            o0.y = fmaxf(acc[i][1] + bias[1], 0.f);
            o0.z = fmaxf(acc[i][2] + bias[2], 0.f);
            o0.w = fmaxf(acc[i][3] + bias[3], 0.f);
            o1.x = fmaxf(acc[i][4] + bias[4], 0.f);
            o1.y = fmaxf(acc[i][5] + bias[5], 0.f);
            o1.z = fmaxf(acc[i][6] + bias[6], 0.f);
            o1.w = fmaxf(acc[i][7] + bias[7], 0.f);
            *(float4*)(h2 + (size_t)r * D + cx) = o0;
            *(float4*)(h2 + (size_t)r * D + cx + 4) = o1;
        }
    }
}

// per-column sum / sumsq partials -> atomics
__global__ __launch_bounds__(256) void k_stats(
        const float* __restrict__ h2, float* __restrict__ ssum,
        float* __restrict__ ssq, int N) {
    int d = threadIdx.x & (D - 1);
    int rg = threadIdx.x >> 7;  // 0..1
    float s = 0.f, q = 0.f;
    for (int r = blockIdx.x * 2 + rg; r < N; r += gridDim.x * 2) {
        float v = h2[(size_t)r * D + d];
        s += v; q += v * v;
    }
    __shared__ float sm[2][D], qm[2][D];
    sm[rg][d] = s; qm[rg][d] = q;
    __syncthreads();
    if (rg == 0) {
        atomicAdd(&ssum[d], sm[0][d] + sm[1][d]);
        atomicAdd(&ssq[d],  qm[0][d] + qm[1][d]);
    }
}

__global__ void k_finalize(const float* __restrict__ ssum, const float* __restrict__ ssq,
                           const float* __restrict__ gam, const float* __restrict__ bet,
                           float* __restrict__ scsh, int N) {
    int d = threadIdx.x;  // exactly D threads
    float mean = ssum[d] / (float)N;
    float var = fmaxf(ssq[d] / (float)N - mean * mean, 0.f);
    float sc = gam[d] * rsqrtf(var + EPSBN);
    scsh[d] = sc;
    scsh[D + d] = bet[d] - mean * sc;
}

__global__ void k_norm(const float* __restrict__ h2, const float* __restrict__ scsh,
                       float* __restrict__ hout, int total4, int relu) {
    int i = blockIdx.x * 256 + threadIdx.x;
    if (i >= total4) return;
    int base = i * 4;
    int d = base & (D - 1);
    float4 v = *(const float4*)(h2 + base);
    float4 o;
    o.x = scsh[d + 0] * v.x + scsh[D + d + 0];
    o.y = scsh[d + 1] * v.y + scsh[D + d + 1];
    o.z = scsh[d + 2] * v.z + scsh[D + d + 2];
    o.w = scsh[d + 3] * v.w + scsh[D + d + 3];
    if (relu) {
        o.x = fmaxf(o.x, 0.f); o.y = fmaxf(o.y, 0.f);
        o.z = fmaxf(o.z, 0.f); o.w = fmaxf(o.w, 0.f);
    }
    *(float4*)(hout + base) = o;
}

// ---------------- host launcher ----------------

extern "C" void kernel_launch(void* const* d_in, const int* in_sizes, int n_in,
                              void* d_out, int out_size, void* d_ws, size_t ws_size,
                              hipStream_t stream) {
    const float* x    = (const float*)d_in[0];
    const int*   ei   = (const int*)d_in[1];
    const float* attr = (const float*)d_in[2];
    const float* W1   = (const float*)d_in[3];
    const float* W2   = (const float*)d_in[4];
    const float* Wm   = (const float*)d_in[5];
    const float* bm   = (const float*)d_in[6];
    const float* gam  = (const float*)d_in[7];
    const float* bet  = (const float*)d_in[8];
    float* out = (float*)d_out;

    const int N = in_sizes[0] / D;
    const int E = in_sizes[1] / 2;
    const int L = in_sizes[3] / (3 * D);

    // workspace carve-up (256B aligned)
    size_t off = 0;
    auto carve = [&](size_t bytes) {
        void* p = (char*)d_ws + off;
        off += (bytes + 255) & ~(size_t)255;
        return p;
    };
    int*   deg     = (int*)carve((size_t)N * 4);
    float* dinv    = (float*)carve((size_t)N * 4);
    int*   row_ptr = (int*)carve((size_t)(N + 1) * 4);
    int*   cursor  = (int*)carve((size_t)N * 4);
    int*   csr_src = (int*)carve((size_t)E * 4);
    float* csr_w   = (float*)carve((size_t)E * 4);
    float* cvals   = (float*)carve((size_t)N * 4 * 4);
    float* agg     = (float*)carve((size_t)N * D * 4);
    float* h2      = (float*)carve((size_t)N * D * 4);
    float* stats   = (float*)carve((size_t)2 * D * 4);  // ssum | ssq
    float* scsh    = (float*)carve((size_t)2 * D * 4);  // scale | shift
    (void)ws_size;

    float* ssum = stats;
    float* ssq  = stats + D;

    // zero init
    hipMemsetAsync(deg, 0, (size_t)N * 4, stream);
    hipMemsetAsync(cvals, 0, (size_t)N * 4 * 4, stream);

    const int eb = (E + 255) / 256;
    const int nb = (N + 255) / 256;
    k_deg<<<eb, 256, 0, stream>>>(ei, E, deg);
    k_dinv<<<nb, 256, 0, stream>>>(deg, dinv, N);
    k_scan<<<1, 1024, 0, stream>>>(deg, row_ptr, cursor, N);
    k_fill<<<eb, 256, 0, stream>>>(ei, attr, dinv, cursor, csr_src, csr_w, cvals, E);

    const int total4 = N * D / 4;
    const int normb = (total4 + 255) / 256;
    const int gemmb = (N + TN - 1) / TN;

    for (int l = 0; l < L; ++l) {
        const float* h_in = (l == 0) ? x : out;
        const float* W1l = W1 + (size_t)l * 3 * D;
        const float* W2l = W2 + (size_t)l * D;
        const float* Wml = Wm + (size_t)l * D * 2 * D;
        const float* bml = bm + (size_t)l * D;

        k_spmm<<<N, 128, 0, stream>>>(h_in, row_ptr, csr_src, csr_w, cvals,
                                      W1l, W2l, agg, N);
        k_gemm<<<gemmb, 256, 0, stream>>>(h_in, agg, Wml, bml, h2, N);

        hipMemsetAsync(stats, 0, (size_t)2 * D * 4, stream);
        k_stats<<<512, 256, 0, stream>>>(h2, ssum, ssq, N);
        k_finalize<<<1, D, 0, stream>>>(ssum, ssq, gam + (size_t)l * D,
                                        bet + (size_t)l * D, scsh, N);
        k_norm<<<normb, 256, 0, stream>>>(h2, scsh, out, total4, (l < L - 1) ? 1 : 0);
    }
}

// Round 2
// 739.450 us; speedup vs baseline: 1.4681x; 1.4681x over previous
//
#include <hip/hip_runtime.h>

#define D 128
#define EPSBN 1e-5f

typedef __attribute__((ext_vector_type(8))) short bf16x8;
typedef __attribute__((ext_vector_type(4))) float f32x4;

static __device__ __forceinline__ unsigned short f2b(float f) {
    unsigned u = __float_as_uint(f);
    unsigned r = u + 0x7FFF + ((u >> 16) & 1);   // RNE
    return (unsigned short)(r >> 16);
}
static __device__ __forceinline__ float b2f_lo(unsigned p) { return __uint_as_float(p << 16); }
static __device__ __forceinline__ float b2f_hi(unsigned p) { return __uint_as_float(p & 0xFFFF0000u); }

// ---------------- setup kernels ----------------

__global__ void k_deg(const int* __restrict__ ei, int E, int* __restrict__ deg) {
    int e = blockIdx.x * 256 + threadIdx.x;
    if (e < E) atomicAdd(&deg[ei[E + e]], 1);
}

__global__ void k_dinv(const int* __restrict__ deg, float* __restrict__ dinv, int N) {
    int v = blockIdx.x * 256 + threadIdx.x;
    if (v < N) {
        int d = deg[v];
        dinv[v] = (d > 0) ? rsqrtf((float)d) : 0.0f;
    }
}

// multi-block exclusive scan: block sums -> scan of sums -> scatter
__global__ void k_bsum(const int* __restrict__ deg, int* __restrict__ bsum, int N) {
    __shared__ int sm[256];
    int t = threadIdx.x, v = blockIdx.x * 256 + t;
    sm[t] = (v < N) ? deg[v] : 0;
    __syncthreads();
    for (int off = 128; off > 0; off >>= 1) {
        if (t < off) sm[t] += sm[t + off];
        __syncthreads();
    }
    if (t == 0) bsum[blockIdx.x] = sm[0];
}

__global__ void k_bscan(const int* __restrict__ bsum, int* __restrict__ boff,
                        int* __restrict__ row_ptr, int NB, int N, int E) {
    __shared__ int sm[256];
    int t = threadIdx.x;
    int v = (t < NB) ? bsum[t] : 0;
    sm[t] = v;
    __syncthreads();
    for (int off = 1; off < 256; off <<= 1) {
        int x = (t >= off) ? sm[t - off] : 0;
        __syncthreads();
        sm[t] += x;
        __syncthreads();
    }
    if (t < NB) boff[t] = sm[t] - v;   // exclusive
    if (t == 0) row_ptr[N] = E;
}

__global__ void k_scatter(const int* __restrict__ deg, const int* __restrict__ boff,
                          int* __restrict__ row_ptr, int* __restrict__ cursor, int N) {
    __shared__ int sm[256];
    int t = threadIdx.x, v = blockIdx.x * 256 + t;
    int val = (v < N) ? deg[v] : 0;
    sm[t] = val;
    __syncthreads();
    for (int off = 1; off < 256; off <<= 1) {
        int x = (t >= off) ? sm[t - off] : 0;
        __syncthreads();
        sm[t] += x;
        __syncthreads();
    }
    if (v < N) {
        int e = boff[blockIdx.x] + sm[t] - val;
        row_ptr[v] = e;
        cursor[v] = e;
    }
}

// fill CSR (packed int2 {src, w}) + accumulate cvals[v][k] = sum norm*attr[e][k]
__global__ void k_fill(const int* __restrict__ ei, const float* __restrict__ attr,
                       const float* __restrict__ dinv, int* __restrict__ cursor,
                       int2* __restrict__ csr, float* __restrict__ cvals, int E) {
    int e = blockIdx.x * 256 + threadIdx.x;
    if (e >= E) return;
    int r = ei[e], c = ei[E + e];
    float nm = dinv[r] * dinv[c];
    int pos = atomicAdd(&cursor[c], 1);
    csr[pos] = make_int2(r, __float_as_int(nm));
    float4 a = *(const float4*)(attr + (size_t)e * 4);
    atomicAdd(&cvals[c * 4 + 0], nm * a.x);
    atomicAdd(&cvals[c * 4 + 1], nm * a.y);
    atomicAdd(&cvals[c * 4 + 2], nm * a.z);
    atomicAdd(&cvals[c * 4 + 3], nm * a.w);
}

// fp32 -> bf16 pack (4 elems / thread)
__global__ void k_cvt(const float* __restrict__ in, unsigned short* __restrict__ outp, int n4) {
    int i = blockIdx.x * 256 + threadIdx.x;
    if (i >= n4) return;
    float4 v = *(const float4*)(in + (size_t)i * 4);
    ushort4 p;
    p.x = f2b(v.x); p.y = f2b(v.y); p.z = f2b(v.z); p.w = f2b(v.w);
    *(ushort4*)(outp + (size_t)i * 4) = p;
}

// ---------------- per-layer kernels ----------------

// one wave per node; lane covers d-pair (2 bf16 per uint)
__global__ __launch_bounds__(256) void k_spmm(
        const unsigned short* __restrict__ hb, const int* __restrict__ row_ptr,
        const int2* __restrict__ csr, const float* __restrict__ cvals,
        const float* __restrict__ W1l, const float* __restrict__ W2l,
        unsigned short* __restrict__ aggb, int N) {
    int lane = threadIdx.x & 63;
    int v = blockIdx.x * 4 + (threadIdx.x >> 6);
    if (v >= N) return;
    int d0 = lane * 2;
    float4 c = *(const float4*)(cvals + (size_t)v * 4);
    float2 w0 = *(const float2*)(W1l + d0);
    float2 w1 = *(const float2*)(W1l + D + d0);
    float2 w2 = *(const float2*)(W1l + 2 * D + d0);
    float2 w3 = *(const float2*)(W2l + d0);
    float a0 = c.x * w0.x + c.y * w1.x + c.z * w2.x + c.w * w3.x;
    float a1 = c.x * w0.y + c.y * w1.y + c.z * w2.y + c.w * w3.y;
    int jb = row_ptr[v], je = row_ptr[v + 1];
    for (int j = jb; j < je; ++j) {
        int2 e = csr[j];
        float w = __int_as_float(e.y);
        unsigned p = *(const unsigned*)(hb + (size_t)e.x * D + d0);
        a0 += w * b2f_lo(p);
        a1 += w * b2f_hi(p);
    }
    unsigned o = ((unsigned)f2b(a1) << 16) | (unsigned)f2b(a0);
    *(unsigned*)(aggb + (size_t)v * D + d0) = o;
}

// h2 = relu([hb, aggb] @ Wmb^T + bm) via bf16 MFMA; h2 fp32 out
#define GROWS 64
#define GBK 64
__global__ __launch_bounds__(256) void k_gemm(
        const unsigned short* __restrict__ hb, const unsigned short* __restrict__ aggb,
        const unsigned short* __restrict__ Wmb, const float* __restrict__ bml,
        float* __restrict__ h2, int N) {
    __shared__ unsigned short As[GROWS][GBK + 8];   // row stride 144B = 9x16B, aligned
    __shared__ unsigned short Bs[D][GBK + 8];
    int tid = threadIdx.x;
    int lane = tid & 63, wave = tid >> 6;
    int n0 = blockIdx.x * GROWS;
    int l15 = lane & 15, q = lane >> 4;
    f32x4 acc[8];
#pragma unroll
    for (int t = 0; t < 8; ++t) acc[t] = (f32x4){0.f, 0.f, 0.f, 0.f};

    for (int kc = 0; kc < 4; ++kc) {
        const unsigned short* src = (kc < 2) ? hb : aggb;
        int k0 = (kc & 1) * GBK;
        // A: 64 rows x 64 k (bf16), 2x16B per thread
#pragma unroll
        for (int i = 0; i < 2; ++i) {
            int idx = tid + i * 256;        // 0..511
            int r = idx >> 3, seg = idx & 7;
            uint4 val = make_uint4(0u, 0u, 0u, 0u);
            if (n0 + r < N) val = *(const uint4*)(src + (size_t)(n0 + r) * D + k0 + seg * 8);
            *(uint4*)&As[r][seg * 8] = val;
        }
        // B: 128 n x 64 k from Wmb[n][kc*64 + ...]
#pragma unroll
        for (int i = 0; i < 4; ++i) {
            int idx = tid + i * 256;        // 0..1023
            int n = idx >> 3, seg = idx & 7;
            *(uint4*)&Bs[n][seg * 8] =
                *(const uint4*)(Wmb + (size_t)n * 256 + kc * GBK + seg * 8);
        }
        __syncthreads();
#pragma unroll
        for (int s = 0; s < 2; ++s) {
            bf16x8 a = *(const bf16x8*)&As[wave * 16 + l15][s * 32 + q * 8];
#pragma unroll
            for (int t = 0; t < 8; ++t) {
                bf16x8 b = *(const bf16x8*)&Bs[t * 16 + l15][s * 32 + q * 8];
                acc[t] = __builtin_amdgcn_mfma_f32_16x16x32_bf16(a, b, acc[t], 0, 0, 0);
            }
        }
        __syncthreads();
    }
    // D[m = wave*16 + q*4 + r][n = t*16 + l15]
#pragma unroll
    for (int t = 0; t < 8; ++t) {
        int n = t * 16 + l15;
        float bias = bml[n];
#pragma unroll
        for (int r = 0; r < 4; ++r) {
            int m = n0 + wave * 16 + q * 4 + r;
            if (m < N) h2[(size_t)m * D + n] = fmaxf(acc[t][r] + bias, 0.f);
        }
    }
}

// per-column sum / sumsq partials -> atomics (h2 fp32)
__global__ __launch_bounds__(256) void k_stats(
        const float* __restrict__ h2, float* __restrict__ ssum,
        float* __restrict__ ssq, int N) {
    int d = threadIdx.x & (D - 1);
    int rg = threadIdx.x >> 7;
    float s = 0.f, q = 0.f;
    for (int r = blockIdx.x * 2 + rg; r < N; r += gridDim.x * 2) {
        float v = h2[(size_t)r * D + d];
        s += v; q += v * v;
    }
    __shared__ float sm[2][D], qm[2][D];
    sm[rg][d] = s; qm[rg][d] = q;
    __syncthreads();
    if (rg == 0) {
        atomicAdd(&ssum[d], sm[0][d] + sm[1][d]);
        atomicAdd(&ssq[d],  qm[0][d] + qm[1][d]);
    }
}

__global__ void k_finalize(const float* __restrict__ ssum, const float* __restrict__ ssq,
                           const float* __restrict__ gam, const float* __restrict__ bet,
                           float* __restrict__ scsh, int N) {
    int d = threadIdx.x;  // exactly D threads
    float mean = ssum[d] / (float)N;
    float var = fmaxf(ssq[d] / (float)N - mean * mean, 0.f);
    float sc = gam[d] * rsqrtf(var + EPSBN);
    scsh[d] = sc;
    scsh[D + d] = bet[d] - mean * sc;
}

// BN affine (+relu) -> bf16 hidden, or fp32 final output
__global__ void k_norm(const float* __restrict__ h2, const float* __restrict__ scsh,
                       unsigned short* __restrict__ hb_out, float* __restrict__ out_f,
                       int total4, int last) {
    int i = blockIdx.x * 256 + threadIdx.x;
    if (i >= total4) return;
    int base = i * 4;
    int d = base & (D - 1);
    float4 v = *(const float4*)(h2 + base);
    float4 o;
    o.x = scsh[d + 0] * v.x + scsh[D + d + 0];
    o.y = scsh[d + 1] * v.y + scsh[D + d + 1];
    o.z = scsh[d + 2] * v.z + scsh[D + d + 2];
    o.w = scsh[d + 3] * v.w + scsh[D + d + 3];
    if (!last) {
        o.x = fmaxf(o.x, 0.f); o.y = fmaxf(o.y, 0.f);
        o.z = fmaxf(o.z, 0.f); o.w = fmaxf(o.w, 0.f);
        ushort4 p;
        p.x = f2b(o.x); p.y = f2b(o.y); p.z = f2b(o.z); p.w = f2b(o.w);
        *(ushort4*)(hb_out + base) = p;
    } else {
        *(float4*)(out_f + base) = o;
    }
}

// ---------------- host launcher ----------------

extern "C" void kernel_launch(void* const* d_in, const int* in_sizes, int n_in,
                              void* d_out, int out_size, void* d_ws, size_t ws_size,
                              hipStream_t stream) {
    const float* x    = (const float*)d_in[0];
    const int*   ei   = (const int*)d_in[1];
    const float* attr = (const float*)d_in[2];
    const float* W1   = (const float*)d_in[3];
    const float* W2   = (const float*)d_in[4];
    const float* Wm   = (const float*)d_in[5];
    const float* bm   = (const float*)d_in[6];
    const float* gam  = (const float*)d_in[7];
    const float* bet  = (const float*)d_in[8];
    float* out = (float*)d_out;

    const int N = in_sizes[0] / D;
    const int E = in_sizes[1] / 2;
    const int L = in_sizes[3] / (3 * D);
    const int NB = (N + 255) / 256;

    size_t off = 0;
    auto carve = [&](size_t bytes) {
        void* p = (char*)d_ws + off;
        off += (bytes + 255) & ~(size_t)255;
        return p;
    };
    int*            deg     = (int*)carve((size_t)N * 4);
    float*          dinv    = (float*)carve((size_t)N * 4);
    int*            row_ptr = (int*)carve((size_t)(N + 1) * 4);
    int*            cursor  = (int*)carve((size_t)N * 4);
    int*            bsum    = (int*)carve((size_t)NB * 4);
    int*            boff    = (int*)carve((size_t)NB * 4);
    int2*           csr     = (int2*)carve((size_t)E * 8);
    float*          cvals   = (float*)carve((size_t)N * 16);
    unsigned short* xb      = (unsigned short*)carve((size_t)N * D * 2);
    unsigned short* hb      = (unsigned short*)carve((size_t)N * D * 2);
    unsigned short* aggb    = (unsigned short*)carve((size_t)N * D * 2);
    unsigned short* Wmb     = (unsigned short*)carve((size_t)L * D * 256 * 2);
    float*          h2      = (float*)carve((size_t)N * D * 4);
    float*          stats   = (float*)carve((size_t)2 * D * 4);
    float*          scsh    = (float*)carve((size_t)2 * D * 4);
    (void)ws_size;

    float* ssum = stats;
    float* ssq  = stats + D;

    hipMemsetAsync(deg, 0, (size_t)N * 4, stream);
    hipMemsetAsync(cvals, 0, (size_t)N * 16, stream);

    const int eb = (E + 255) / 256;
    k_deg<<<eb, 256, 0, stream>>>(ei, E, deg);
    k_dinv<<<NB, 256, 0, stream>>>(deg, dinv, N);
    k_bsum<<<NB, 256, 0, stream>>>(deg, bsum, N);
    k_bscan<<<1, 256, 0, stream>>>(bsum, boff, row_ptr, NB, N, E);
    k_scatter<<<NB, 256, 0, stream>>>(deg, boff, row_ptr, cursor, N);
    k_fill<<<eb, 256, 0, stream>>>(ei, attr, dinv, cursor, csr, cvals, E);

    const int xq = N * D / 4;
    k_cvt<<<(xq + 255) / 256, 256, 0, stream>>>(x, xb, xq);
    const int wq = L * D * 256 / 4;
    k_cvt<<<(wq + 255) / 256, 256, 0, stream>>>(Wm, Wmb, wq);

    const int total4 = N * D / 4;
    const int normb = (total4 + 255) / 256;
    const int gemmb = (N + GROWS - 1) / GROWS;
    const int spmmb = (N + 3) / 4;

    for (int l = 0; l < L; ++l) {
        const unsigned short* in = (l == 0) ? xb : hb;
        const float* W1l = W1 + (size_t)l * 3 * D;
        const float* W2l = W2 + (size_t)l * D;
        const unsigned short* Wml = Wmb + (size_t)l * D * 256;
        const float* bml = bm + (size_t)l * D;

        k_spmm<<<spmmb, 256, 0, stream>>>(in, row_ptr, csr, cvals, W1l, W2l, aggb, N);
        k_gemm<<<gemmb, 256, 0, stream>>>(in, aggb, Wml, bml, h2, N);

        hipMemsetAsync(stats, 0, (size_t)2 * D * 4, stream);
        k_stats<<<512, 256, 0, stream>>>(h2, ssum, ssq, N);
        k_finalize<<<1, D, 0, stream>>>(ssum, ssq, gam + (size_t)l * D,
                                        bet + (size_t)l * D, scsh, N);
        k_norm<<<normb, 256, 0, stream>>>(h2, scsh, hb, out, total4, (l < L - 1) ? 0 : 1);
    }
}

// Round 3
// 598.545 us; speedup vs baseline: 1.8137x; 1.2354x over previous
//
#include <hip/hip_runtime.h>

#define D 128
#define EPSBN 1e-5f

typedef __attribute__((ext_vector_type(8))) short bf16x8;
typedef __attribute__((ext_vector_type(4))) float f32x4;

static __device__ __forceinline__ unsigned short f2b(float f) {
    unsigned u = __float_as_uint(f);
    unsigned r = u + 0x7FFF + ((u >> 16) & 1);   // RNE
    return (unsigned short)(r >> 16);
}
static __device__ __forceinline__ float b2f_lo(unsigned p) { return __uint_as_float(p << 16); }
static __device__ __forceinline__ float b2f_hi(unsigned p) { return __uint_as_float(p & 0xFFFF0000u); }

// ---------------- setup kernels ----------------

__global__ void k_deg(const int* __restrict__ ei, int E, int* __restrict__ deg) {
    int e = blockIdx.x * 256 + threadIdx.x;
    if (e < E) atomicAdd(&deg[ei[E + e]], 1);
}

__global__ void k_dinv(const int* __restrict__ deg, float* __restrict__ dinv, int N) {
    int v = blockIdx.x * 256 + threadIdx.x;
    if (v < N) {
        int d = deg[v];
        dinv[v] = (d > 0) ? rsqrtf((float)d) : 0.0f;
    }
}

// multi-block exclusive scan: block sums -> scan of sums -> scatter
__global__ void k_bsum(const int* __restrict__ deg, int* __restrict__ bsum, int N) {
    __shared__ int sm[256];
    int t = threadIdx.x, v = blockIdx.x * 256 + t;
    sm[t] = (v < N) ? deg[v] : 0;
    __syncthreads();
    for (int off = 128; off > 0; off >>= 1) {
        if (t < off) sm[t] += sm[t + off];
        __syncthreads();
    }
    if (t == 0) bsum[blockIdx.x] = sm[0];
}

__global__ void k_bscan(const int* __restrict__ bsum, int* __restrict__ boff,
                        int* __restrict__ row_ptr, int NB, int N, int E) {
    __shared__ int sm[256];
    int t = threadIdx.x;
    int v = (t < NB) ? bsum[t] : 0;
    sm[t] = v;
    __syncthreads();
    for (int off = 1; off < 256; off <<= 1) {
        int x = (t >= off) ? sm[t - off] : 0;
        __syncthreads();
        sm[t] += x;
        __syncthreads();
    }
    if (t < NB) boff[t] = sm[t] - v;   // exclusive
    if (t == 0) row_ptr[N] = E;
}

__global__ void k_scatter(const int* __restrict__ deg, const int* __restrict__ boff,
                          int* __restrict__ row_ptr, int* __restrict__ cursor, int N) {
    __shared__ int sm[256];
    int t = threadIdx.x, v = blockIdx.x * 256 + t;
    int val = (v < N) ? deg[v] : 0;
    sm[t] = val;
    __syncthreads();
    for (int off = 1; off < 256; off <<= 1) {
        int x = (t >= off) ? sm[t - off] : 0;
        __syncthreads();
        sm[t] += x;
        __syncthreads();
    }
    if (v < N) {
        int e = boff[blockIdx.x] + sm[t] - val;
        row_ptr[v] = e;
        cursor[v] = e;
    }
}

// CSR fill only: (src, edge_id). No attr read, no cvals atomics.
__global__ void k_fill(const int* __restrict__ ei, int* __restrict__ cursor,
                       int2* __restrict__ csr, int E) {
    int e = blockIdx.x * 256 + threadIdx.x;
    if (e >= E) return;
    int r = ei[e], c = ei[E + e];
    int pos = atomicAdd(&cursor[c], 1);
    csr[pos] = make_int2(r, e);
}

// cvals[v] = sum_{e->v} nm_e * attr[e][0..3]  (atomic-free CSR walk, once)
__global__ void k_cvals(const int* __restrict__ row_ptr, const int2* __restrict__ csr,
                        const float* __restrict__ dinv, const float* __restrict__ attr,
                        float4* __restrict__ cvals, int N) {
    int v = blockIdx.x * 256 + threadIdx.x;
    if (v >= N) return;
    float dv = dinv[v];
    int jb = row_ptr[v], je = row_ptr[v + 1];
    float4 acc = make_float4(0.f, 0.f, 0.f, 0.f);
    for (int j = jb; j < je; ++j) {
        int2 e = csr[j];
        float nm = dinv[e.x] * dv;
        float4 a = *(const float4*)(attr + (size_t)e.y * 4);
        acc.x += nm * a.x; acc.y += nm * a.y;
        acc.z += nm * a.z; acc.w += nm * a.w;
    }
    cvals[v] = acc;
}

// fp32 -> bf16 pack (4 elems / thread)
__global__ void k_cvt(const float* __restrict__ in, unsigned short* __restrict__ outp, int n4) {
    int i = blockIdx.x * 256 + threadIdx.x;
    if (i >= n4) return;
    float4 v = *(const float4*)(in + (size_t)i * 4);
    ushort4 p;
    p.x = f2b(v.x); p.y = f2b(v.y); p.z = f2b(v.z); p.w = f2b(v.w);
    *(ushort4*)(outp + (size_t)i * 4) = p;
}

// ---------------- per-layer kernels ----------------

// wave per node, 4 edges/iteration: each 16-lane quarter handles one edge,
// lane covers 8 dims via uint4 (16 lanes x 16B = 256B row). Cross-quarter
// shuffle reduction at the end.
__global__ __launch_bounds__(256) void k_spmm(
        const unsigned short* __restrict__ hb, const int* __restrict__ row_ptr,
        const int2* __restrict__ csr, const float* __restrict__ dinv,
        const float4* __restrict__ cvals,
        const float* __restrict__ W1l, const float* __restrict__ W2l,
        unsigned short* __restrict__ aggb, int N) {
    int lane = threadIdx.x & 63;
    int v = blockIdx.x * 4 + (threadIdx.x >> 6);
    if (v >= N) return;
    int qw = lane >> 4;       // quarter 0..3 -> edge j0+qw
    int l4 = lane & 15;       // position within quarter
    int d0 = l4 * 8;          // 8 dims per lane
    float dv = dinv[v];
    int jb = row_ptr[v], je = row_ptr[v + 1];

    float a[8];
#pragma unroll
    for (int i = 0; i < 8; ++i) a[i] = 0.f;

    for (int j0 = jb; j0 < je; j0 += 4) {
        int j = j0 + qw;
        bool ok = (j < je);
        int2 e = csr[ok ? j : jb];
        float nm = ok ? dinv[e.x] * dv : 0.f;
        uint4 p = *(const uint4*)(hb + (size_t)e.x * D + d0);
        a[0] += nm * b2f_lo(p.x); a[1] += nm * b2f_hi(p.x);
        a[2] += nm * b2f_lo(p.y); a[3] += nm * b2f_hi(p.y);
        a[4] += nm * b2f_lo(p.z); a[5] += nm * b2f_hi(p.z);
        a[6] += nm * b2f_lo(p.w); a[7] += nm * b2f_hi(p.w);
    }
    // reduce across quarters (lanes L, L+16, L+32, L+48)
#pragma unroll
    for (int i = 0; i < 8; ++i) {
        a[i] += __shfl_xor(a[i], 16);
        a[i] += __shfl_xor(a[i], 32);
    }
    if (qw == 0) {
        float4 c = cvals[v];
        float4 wa0 = *(const float4*)(W1l + d0);
        float4 wa1 = *(const float4*)(W1l + d0 + 4);
        float4 wb0 = *(const float4*)(W1l + D + d0);
        float4 wb1 = *(const float4*)(W1l + D + d0 + 4);
        float4 wc0 = *(const float4*)(W1l + 2 * D + d0);
        float4 wc1 = *(const float4*)(W1l + 2 * D + d0 + 4);
        float4 wd0 = *(const float4*)(W2l + d0);
        float4 wd1 = *(const float4*)(W2l + d0 + 4);
        a[0] += c.x * wa0.x + c.y * wb0.x + c.z * wc0.x + c.w * wd0.x;
        a[1] += c.x * wa0.y + c.y * wb0.y + c.z * wc0.y + c.w * wd0.y;
        a[2] += c.x * wa0.z + c.y * wb0.z + c.z * wc0.z + c.w * wd0.z;
        a[3] += c.x * wa0.w + c.y * wb0.w + c.z * wc0.w + c.w * wd0.w;
        a[4] += c.x * wa1.x + c.y * wb1.x + c.z * wc1.x + c.w * wd1.x;
        a[5] += c.x * wa1.y + c.y * wb1.y + c.z * wc1.y + c.w * wd1.y;
        a[6] += c.x * wa1.z + c.y * wb1.z + c.z * wc1.z + c.w * wd1.z;
        a[7] += c.x * wa1.w + c.y * wb1.w + c.z * wc1.w + c.w * wd1.w;
        uint4 o;
        o.x = ((unsigned)f2b(a[1]) << 16) | (unsigned)f2b(a[0]);
        o.y = ((unsigned)f2b(a[3]) << 16) | (unsigned)f2b(a[2]);
        o.z = ((unsigned)f2b(a[5]) << 16) | (unsigned)f2b(a[4]);
        o.w = ((unsigned)f2b(a[7]) << 16) | (unsigned)f2b(a[6]);
        *(uint4*)(aggb + (size_t)v * D + d0) = o;
    }
}

// h2 = relu([hb, aggb] @ Wmb^T + bm) via bf16 MFMA; h2 fp32 out
#define GROWS 64
#define GBK 64
__global__ __launch_bounds__(256) void k_gemm(
        const unsigned short* __restrict__ hb, const unsigned short* __restrict__ aggb,
        const unsigned short* __restrict__ Wmb, const float* __restrict__ bml,
        float* __restrict__ h2, int N) {
    __shared__ unsigned short As[GROWS][GBK + 8];
    __shared__ unsigned short Bs[D][GBK + 8];
    int tid = threadIdx.x;
    int lane = tid & 63, wave = tid >> 6;
    int n0 = blockIdx.x * GROWS;
    int l15 = lane & 15, q = lane >> 4;
    f32x4 acc[8];
#pragma unroll
    for (int t = 0; t < 8; ++t) acc[t] = (f32x4){0.f, 0.f, 0.f, 0.f};

    for (int kc = 0; kc < 4; ++kc) {
        const unsigned short* src = (kc < 2) ? hb : aggb;
        int k0 = (kc & 1) * GBK;
#pragma unroll
        for (int i = 0; i < 2; ++i) {
            int idx = tid + i * 256;
            int r = idx >> 3, seg = idx & 7;
            uint4 val = make_uint4(0u, 0u, 0u, 0u);
            if (n0 + r < N) val = *(const uint4*)(src + (size_t)(n0 + r) * D + k0 + seg * 8);
            *(uint4*)&As[r][seg * 8] = val;
        }
#pragma unroll
        for (int i = 0; i < 4; ++i) {
            int idx = tid + i * 256;
            int n = idx >> 3, seg = idx & 7;
            *(uint4*)&Bs[n][seg * 8] =
                *(const uint4*)(Wmb + (size_t)n * 256 + kc * GBK + seg * 8);
        }
        __syncthreads();
#pragma unroll
        for (int s = 0; s < 2; ++s) {
            bf16x8 a = *(const bf16x8*)&As[wave * 16 + l15][s * 32 + q * 8];
#pragma unroll
            for (int t = 0; t < 8; ++t) {
                bf16x8 b = *(const bf16x8*)&Bs[t * 16 + l15][s * 32 + q * 8];
                acc[t] = __builtin_amdgcn_mfma_f32_16x16x32_bf16(a, b, acc[t], 0, 0, 0);
            }
        }
        __syncthreads();
    }
#pragma unroll
    for (int t = 0; t < 8; ++t) {
        int n = t * 16 + l15;
        float bias = bml[n];
#pragma unroll
        for (int r = 0; r < 4; ++r) {
            int m = n0 + wave * 16 + q * 4 + r;
            if (m < N) h2[(size_t)m * D + n] = fmaxf(acc[t][r] + bias, 0.f);
        }
    }
}

// per-column sum / sumsq partials -> atomics (h2 fp32)
__global__ __launch_bounds__(256) void k_stats(
        const float* __restrict__ h2, float* __restrict__ ssum,
        float* __restrict__ ssq, int N) {
    int d = threadIdx.x & (D - 1);
    int rg = threadIdx.x >> 7;
    float s = 0.f, q = 0.f;
    for (int r = blockIdx.x * 2 + rg; r < N; r += gridDim.x * 2) {
        float v = h2[(size_t)r * D + d];
        s += v; q += v * v;
    }
    __shared__ float sm[2][D], qm[2][D];
    sm[rg][d] = s; qm[rg][d] = q;
    __syncthreads();
    if (rg == 0) {
        atomicAdd(&ssum[d], sm[0][d] + sm[1][d]);
        atomicAdd(&ssq[d],  qm[0][d] + qm[1][d]);
    }
}

__global__ void k_finalize(const float* __restrict__ ssum, const float* __restrict__ ssq,
                           const float* __restrict__ gam, const float* __restrict__ bet,
                           float* __restrict__ scsh, int N) {
    int d = threadIdx.x;
    float mean = ssum[d] / (float)N;
    float var = fmaxf(ssq[d] / (float)N - mean * mean, 0.f);
    float sc = gam[d] * rsqrtf(var + EPSBN);
    scsh[d] = sc;
    scsh[D + d] = bet[d] - mean * sc;
}

__global__ void k_norm(const float* __restrict__ h2, const float* __restrict__ scsh,
                       unsigned short* __restrict__ hb_out, float* __restrict__ out_f,
                       int total4, int last) {
    int i = blockIdx.x * 256 + threadIdx.x;
    if (i >= total4) return;
    int base = i * 4;
    int d = base & (D - 1);
    float4 v = *(const float4*)(h2 + base);
    float4 o;
    o.x = scsh[d + 0] * v.x + scsh[D + d + 0];
    o.y = scsh[d + 1] * v.y + scsh[D + d + 1];
    o.z = scsh[d + 2] * v.z + scsh[D + d + 2];
    o.w = scsh[d + 3] * v.w + scsh[D + d + 3];
    if (!last) {
        o.x = fmaxf(o.x, 0.f); o.y = fmaxf(o.y, 0.f);
        o.z = fmaxf(o.z, 0.f); o.w = fmaxf(o.w, 0.f);
        ushort4 p;
        p.x = f2b(o.x); p.y = f2b(o.y); p.z = f2b(o.z); p.w = f2b(o.w);
        *(ushort4*)(hb_out + base) = p;
    } else {
        *(float4*)(out_f + base) = o;
    }
}

// ---------------- host launcher ----------------

extern "C" void kernel_launch(void* const* d_in, const int* in_sizes, int n_in,
                              void* d_out, int out_size, void* d_ws, size_t ws_size,
                              hipStream_t stream) {
    const float* x    = (const float*)d_in[0];
    const int*   ei   = (const int*)d_in[1];
    const float* attr = (const float*)d_in[2];
    const float* W1   = (const float*)d_in[3];
    const float* W2   = (const float*)d_in[4];
    const float* Wm   = (const float*)d_in[5];
    const float* bm   = (const float*)d_in[6];
    const float* gam  = (const float*)d_in[7];
    const float* bet  = (const float*)d_in[8];
    float* out = (float*)d_out;

    const int N = in_sizes[0] / D;
    const int E = in_sizes[1] / 2;
    const int L = in_sizes[3] / (3 * D);
    const int NB = (N + 255) / 256;

    size_t off = 0;
    auto carve = [&](size_t bytes) {
        void* p = (char*)d_ws + off;
        off += (bytes + 255) & ~(size_t)255;
        return p;
    };
    int*            deg     = (int*)carve((size_t)N * 4);
    float*          dinv    = (float*)carve((size_t)N * 4);
    int*            row_ptr = (int*)carve((size_t)(N + 1) * 4);
    int*            cursor  = (int*)carve((size_t)N * 4);
    int*            bsum    = (int*)carve((size_t)NB * 4);
    int*            boff    = (int*)carve((size_t)NB * 4);
    int2*           csr     = (int2*)carve((size_t)(E + 4) * 8);  // +pad for clamped reads
    float4*         cvals   = (float4*)carve((size_t)N * 16);
    unsigned short* xb      = (unsigned short*)carve((size_t)N * D * 2);
    unsigned short* hb      = (unsigned short*)carve((size_t)N * D * 2);
    unsigned short* aggb    = (unsigned short*)carve((size_t)N * D * 2);
    unsigned short* Wmb     = (unsigned short*)carve((size_t)L * D * 256 * 2);
    float*          h2      = (float*)carve((size_t)N * D * 4);
    float*          stats   = (float*)carve((size_t)2 * D * 4);
    float*          scsh    = (float*)carve((size_t)2 * D * 4);
    (void)ws_size;

    float* ssum = stats;
    float* ssq  = stats + D;

    hipMemsetAsync(deg, 0, (size_t)N * 4, stream);

    const int eb = (E + 255) / 256;
    k_deg<<<eb, 256, 0, stream>>>(ei, E, deg);
    k_dinv<<<NB, 256, 0, stream>>>(deg, dinv, N);
    k_bsum<<<NB, 256, 0, stream>>>(deg, bsum, N);
    k_bscan<<<1, 256, 0, stream>>>(bsum, boff, row_ptr, NB, N, E);
    k_scatter<<<NB, 256, 0, stream>>>(deg, boff, row_ptr, cursor, N);
    k_fill<<<eb, 256, 0, stream>>>(ei, cursor, csr, E);
    k_cvals<<<NB, 256, 0, stream>>>(row_ptr, csr, dinv, attr, cvals, N);

    const int xq = N * D / 4;
    k_cvt<<<(xq + 255) / 256, 256, 0, stream>>>(x, xb, xq);
    const int wq = L * D * 256 / 4;
    k_cvt<<<(wq + 255) / 256, 256, 0, stream>>>(Wm, Wmb, wq);

    const int total4 = N * D / 4;
    const int normb = (total4 + 255) / 256;
    const int gemmb = (N + GROWS - 1) / GROWS;
    const int spmmb = (N + 3) / 4;

    for (int l = 0; l < L; ++l) {
        const unsigned short* in = (l == 0) ? xb : hb;
        const float* W1l = W1 + (size_t)l * 3 * D;
        const float* W2l = W2 + (size_t)l * D;
        const unsigned short* Wml = Wmb + (size_t)l * D * 256;
        const float* bml = bm + (size_t)l * D;

        k_spmm<<<spmmb, 256, 0, stream>>>(in, row_ptr, csr, dinv, cvals,
                                          W1l, W2l, aggb, N);
        k_gemm<<<gemmb, 256, 0, stream>>>(in, aggb, Wml, bml, h2, N);

        hipMemsetAsync(stats, 0, (size_t)2 * D * 4, stream);
        k_stats<<<512, 256, 0, stream>>>(h2, ssum, ssq, N);
        k_finalize<<<1, D, 0, stream>>>(ssum, ssq, gam + (size_t)l * D,
                                        bet + (size_t)l * D, scsh, N);
        k_norm<<<normb, 256, 0, stream>>>(h2, scsh, hb, out, total4, (l < L - 1) ? 0 : 1);
    }
}

// Round 4
// 467.486 us; speedup vs baseline: 2.3221x; 1.2803x over previous
//
#include <hip/hip_runtime.h>

#define D 128
#define EPSBN 1e-5f
#define PB 800   // padded partial-buffer stride (>= gemm block count 782)

typedef __attribute__((ext_vector_type(8))) short bf16x8;
typedef __attribute__((ext_vector_type(4))) float f32x4;

static __device__ __forceinline__ unsigned short f2b(float f) {
    unsigned u = __float_as_uint(f);
    unsigned r = u + 0x7FFF + ((u >> 16) & 1);   // RNE
    return (unsigned short)(r >> 16);
}
static __device__ __forceinline__ float b2f_lo(unsigned p) { return __uint_as_float(p << 16); }
static __device__ __forceinline__ float b2f_hi(unsigned p) { return __uint_as_float(p & 0xFFFF0000u); }

// ---------------- setup kernels ----------------

__global__ void k_deg(const int* __restrict__ ei, int E, int* __restrict__ deg) {
    int e = blockIdx.x * 256 + threadIdx.x;
    if (e < E) atomicAdd(&deg[ei[E + e]], 1);
}

__global__ void k_dinv(const int* __restrict__ deg, float* __restrict__ dinv, int N) {
    int v = blockIdx.x * 256 + threadIdx.x;
    if (v < N) {
        int d = deg[v];
        dinv[v] = (d > 0) ? rsqrtf((float)d) : 0.0f;
    }
}

__global__ void k_bsum(const int* __restrict__ deg, int* __restrict__ bsum, int N) {
    __shared__ int sm[256];
    int t = threadIdx.x, v = blockIdx.x * 256 + t;
    sm[t] = (v < N) ? deg[v] : 0;
    __syncthreads();
    for (int off = 128; off > 0; off >>= 1) {
        if (t < off) sm[t] += sm[t + off];
        __syncthreads();
    }
    if (t == 0) bsum[blockIdx.x] = sm[0];
}

__global__ void k_bscan(const int* __restrict__ bsum, int* __restrict__ boff,
                        int* __restrict__ row_ptr, int NB, int N, int E) {
    __shared__ int sm[256];
    int t = threadIdx.x;
    int v = (t < NB) ? bsum[t] : 0;
    sm[t] = v;
    __syncthreads();
    for (int off = 1; off < 256; off <<= 1) {
        int x = (t >= off) ? sm[t - off] : 0;
        __syncthreads();
        sm[t] += x;
        __syncthreads();
    }
    if (t < NB) boff[t] = sm[t] - v;   // exclusive
    if (t == 0) row_ptr[N] = E;
}

__global__ void k_scatter(const int* __restrict__ deg, const int* __restrict__ boff,
                          int* __restrict__ row_ptr, int* __restrict__ cursor, int N) {
    __shared__ int sm[256];
    int t = threadIdx.x, v = blockIdx.x * 256 + t;
    int val = (v < N) ? deg[v] : 0;
    sm[t] = val;
    __syncthreads();
    for (int off = 1; off < 256; off <<= 1) {
        int x = (t >= off) ? sm[t - off] : 0;
        __syncthreads();
        sm[t] += x;
        __syncthreads();
    }
    if (v < N) {
        int e = boff[blockIdx.x] + sm[t] - val;
        row_ptr[v] = e;
        cursor[v] = e;
    }
}

// CSR fill: (src, edge_id)
__global__ void k_fill(const int* __restrict__ ei, int* __restrict__ cursor,
                       int2* __restrict__ csr, int E) {
    int e = blockIdx.x * 256 + threadIdx.x;
    if (e >= E) return;
    int r = ei[e], c = ei[E + e];
    int pos = atomicAdd(&cursor[c], 1);
    csr[pos] = make_int2(r, e);
}

// cvals[v] = sum nm_e * attr[e]; rewrites csr[j] = (src, nm) so per-layer
// spmm never touches dinv/attr again.
__global__ void k_cvals(const int* __restrict__ row_ptr, int2* __restrict__ csr,
                        const float* __restrict__ dinv, const float* __restrict__ attr,
                        float4* __restrict__ cvals, int N) {
    int v = blockIdx.x * 256 + threadIdx.x;
    if (v >= N) return;
    float dv = dinv[v];
    int jb = row_ptr[v], je = row_ptr[v + 1];
    float4 acc = make_float4(0.f, 0.f, 0.f, 0.f);
    for (int j = jb; j < je; ++j) {
        int2 e = csr[j];
        float nm = dinv[e.x] * dv;
        float4 a = *(const float4*)(attr + (size_t)e.y * 4);
        acc.x += nm * a.x; acc.y += nm * a.y;
        acc.z += nm * a.z; acc.w += nm * a.w;
        csr[j] = make_int2(e.x, __float_as_int(nm));
    }
    cvals[v] = acc;
}

// fp32 -> bf16 pack (4 elems / thread)
__global__ void k_cvt(const float* __restrict__ in, unsigned short* __restrict__ outp, int n4) {
    int i = blockIdx.x * 256 + threadIdx.x;
    if (i >= n4) return;
    float4 v = *(const float4*)(in + (size_t)i * 4);
    ushort4 p;
    p.x = f2b(v.x); p.y = f2b(v.y); p.z = f2b(v.z); p.w = f2b(v.w);
    *(ushort4*)(outp + (size_t)i * 4) = p;
}

// ---------------- per-layer kernels ----------------

// wave per node, 4 edges/iter via 16-lane quarters; csr = (src, nm)
__global__ __launch_bounds__(256) void k_spmm(
        const unsigned short* __restrict__ hb, const int* __restrict__ row_ptr,
        const int2* __restrict__ csr, const float4* __restrict__ cvals,
        const float* __restrict__ W1l, const float* __restrict__ W2l,
        unsigned short* __restrict__ aggb, int N) {
    int lane = threadIdx.x & 63;
    int v = blockIdx.x * 4 + (threadIdx.x >> 6);
    if (v >= N) return;
    int qw = lane >> 4;
    int l4 = lane & 15;
    int d0 = l4 * 8;
    int jb = row_ptr[v], je = row_ptr[v + 1];

    float a[8];
#pragma unroll
    for (int i = 0; i < 8; ++i) a[i] = 0.f;

    for (int j0 = jb; j0 < je; j0 += 4) {
        int j = j0 + qw;
        bool ok = (j < je);
        int2 e = csr[ok ? j : jb];
        float nm = ok ? __int_as_float(e.y) : 0.f;
        uint4 p = *(const uint4*)(hb + (size_t)e.x * D + d0);
        a[0] += nm * b2f_lo(p.x); a[1] += nm * b2f_hi(p.x);
        a[2] += nm * b2f_lo(p.y); a[3] += nm * b2f_hi(p.y);
        a[4] += nm * b2f_lo(p.z); a[5] += nm * b2f_hi(p.z);
        a[6] += nm * b2f_lo(p.w); a[7] += nm * b2f_hi(p.w);
    }
#pragma unroll
    for (int i = 0; i < 8; ++i) {
        a[i] += __shfl_xor(a[i], 16);
        a[i] += __shfl_xor(a[i], 32);
    }
    if (qw == 0) {
        float4 c = cvals[v];
        float4 wa0 = *(const float4*)(W1l + d0);
        float4 wa1 = *(const float4*)(W1l + d0 + 4);
        float4 wb0 = *(const float4*)(W1l + D + d0);
        float4 wb1 = *(const float4*)(W1l + D + d0 + 4);
        float4 wc0 = *(const float4*)(W1l + 2 * D + d0);
        float4 wc1 = *(const float4*)(W1l + 2 * D + d0 + 4);
        float4 wd0 = *(const float4*)(W2l + d0);
        float4 wd1 = *(const float4*)(W2l + d0 + 4);
        a[0] += c.x * wa0.x + c.y * wb0.x + c.z * wc0.x + c.w * wd0.x;
        a[1] += c.x * wa0.y + c.y * wb0.y + c.z * wc0.y + c.w * wd0.y;
        a[2] += c.x * wa0.z + c.y * wb0.z + c.z * wc0.z + c.w * wd0.z;
        a[3] += c.x * wa0.w + c.y * wb0.w + c.z * wc0.w + c.w * wd0.w;
        a[4] += c.x * wa1.x + c.y * wb1.x + c.z * wc1.x + c.w * wd1.x;
        a[5] += c.x * wa1.y + c.y * wb1.y + c.z * wc1.y + c.w * wd1.y;
        a[6] += c.x * wa1.z + c.y * wb1.z + c.z * wc1.z + c.w * wd1.z;
        a[7] += c.x * wa1.w + c.y * wb1.w + c.z * wc1.w + c.w * wd1.w;
        uint4 o;
        o.x = ((unsigned)f2b(a[1]) << 16) | (unsigned)f2b(a[0]);
        o.y = ((unsigned)f2b(a[3]) << 16) | (unsigned)f2b(a[2]);
        o.z = ((unsigned)f2b(a[5]) << 16) | (unsigned)f2b(a[4]);
        o.w = ((unsigned)f2b(a[7]) << 16) | (unsigned)f2b(a[6]);
        *(uint4*)(aggb + (size_t)v * D + d0) = o;
    }
}

// h2 = relu([hb, aggb] @ Wmb^T + bm) via bf16 MFMA; fused per-column
// sum/sumsq partials (non-atomic) -> pbuf[n][block]
#define GROWS 64
#define GBK 64
__global__ __launch_bounds__(256) void k_gemm(
        const unsigned short* __restrict__ hb, const unsigned short* __restrict__ aggb,
        const unsigned short* __restrict__ Wmb, const float* __restrict__ bml,
        float* __restrict__ h2, float* __restrict__ pbuf, int N) {
    __shared__ unsigned short As[GROWS][GBK + 8];
    __shared__ unsigned short Bs[D][GBK + 8];
    __shared__ float sred[2][4][D];
    int tid = threadIdx.x;
    int lane = tid & 63, wave = tid >> 6;
    int n0 = blockIdx.x * GROWS;
    int l15 = lane & 15, q = lane >> 4;
    f32x4 acc[8];
#pragma unroll
    for (int t = 0; t < 8; ++t) acc[t] = (f32x4){0.f, 0.f, 0.f, 0.f};

    for (int kc = 0; kc < 4; ++kc) {
        const unsigned short* src = (kc < 2) ? hb : aggb;
        int k0 = (kc & 1) * GBK;
#pragma unroll
        for (int i = 0; i < 2; ++i) {
            int idx = tid + i * 256;
            int r = idx >> 3, seg = idx & 7;
            uint4 val = make_uint4(0u, 0u, 0u, 0u);
            if (n0 + r < N) val = *(const uint4*)(src + (size_t)(n0 + r) * D + k0 + seg * 8);
            *(uint4*)&As[r][seg * 8] = val;
        }
#pragma unroll
        for (int i = 0; i < 4; ++i) {
            int idx = tid + i * 256;
            int n = idx >> 3, seg = idx & 7;
            *(uint4*)&Bs[n][seg * 8] =
                *(const uint4*)(Wmb + (size_t)n * 256 + kc * GBK + seg * 8);
        }
        __syncthreads();
#pragma unroll
        for (int s = 0; s < 2; ++s) {
            bf16x8 a = *(const bf16x8*)&As[wave * 16 + l15][s * 32 + q * 8];
#pragma unroll
            for (int t = 0; t < 8; ++t) {
                bf16x8 b = *(const bf16x8*)&Bs[t * 16 + l15][s * 32 + q * 8];
                acc[t] = __builtin_amdgcn_mfma_f32_16x16x32_bf16(a, b, acc[t], 0, 0, 0);
            }
        }
        __syncthreads();
    }
    // epilogue: bias+relu, store h2, accumulate column partials
    bool full = (n0 + GROWS <= N);
    float ps[8], pq[8];
#pragma unroll
    for (int t = 0; t < 8; ++t) {
        int n = t * 16 + l15;
        float bias = bml[n];
        float s = 0.f, qs = 0.f;
#pragma unroll
        for (int r = 0; r < 4; ++r) {
            int m = n0 + wave * 16 + q * 4 + r;
            float v = fmaxf(acc[t][r] + bias, 0.f);
            if (full || m < N) {
                h2[(size_t)m * D + n] = v;
                s += v; qs += v * v;
            }
        }
        ps[t] = s; pq[t] = qs;
    }
#pragma unroll
    for (int t = 0; t < 8; ++t) {
        ps[t] += __shfl_xor(ps[t], 16); ps[t] += __shfl_xor(ps[t], 32);
        pq[t] += __shfl_xor(pq[t], 16); pq[t] += __shfl_xor(pq[t], 32);
    }
    if (q == 0) {
#pragma unroll
        for (int t = 0; t < 8; ++t) {
            sred[0][wave][t * 16 + l15] = ps[t];
            sred[1][wave][t * 16 + l15] = pq[t];
        }
    }
    __syncthreads();
    if (tid < D) {
        float s = sred[0][0][tid] + sred[0][1][tid] + sred[0][2][tid] + sred[0][3][tid];
        pbuf[(size_t)tid * PB + blockIdx.x] = s;
    } else {
        int n = tid - D;
        float qv = sred[1][0][n] + sred[1][1][n] + sred[1][2][n] + sred[1][3][n];
        pbuf[(size_t)(n + D) * PB + blockIdx.x] = qv;
    }
}

// fold pbuf partials -> scale/shift directly (absorbs finalize)
__global__ __launch_bounds__(128) void k_reduce(
        const float* __restrict__ pbuf, const float* __restrict__ gam,
        const float* __restrict__ bet, float* __restrict__ scsh, int nb, int N) {
    int n = blockIdx.x;   // 0..127
    int t = threadIdx.x;  // 0..127
    float s = 0.f, qv = 0.f;
    for (int b = t; b < nb; b += 128) {
        s  += pbuf[(size_t)n * PB + b];
        qv += pbuf[(size_t)(n + D) * PB + b];
    }
#pragma unroll
    for (int off = 32; off > 0; off >>= 1) {
        s += __shfl_down(s, off);
        qv += __shfl_down(qv, off);
    }
    __shared__ float aux[4];
    if ((t & 63) == 0) { aux[t >> 6] = s; aux[2 + (t >> 6)] = qv; }
    __syncthreads();
    if (t == 0) {
        float S = aux[0] + aux[1], Q = aux[2] + aux[3];
        float mean = S / (float)N;
        float var = fmaxf(Q / (float)N - mean * mean, 0.f);
        float sc = gam[n] * rsqrtf(var + EPSBN);
        scsh[n] = sc;
        scsh[D + n] = bet[n] - mean * sc;
    }
}

__global__ void k_norm(const float* __restrict__ h2, const float* __restrict__ scsh,
                       unsigned short* __restrict__ hb_out, float* __restrict__ out_f,
                       int total4, int last) {
    int i = blockIdx.x * 256 + threadIdx.x;
    if (i >= total4) return;
    int base = i * 4;
    int d = base & (D - 1);
    float4 v = *(const float4*)(h2 + base);
    float4 o;
    o.x = scsh[d + 0] * v.x + scsh[D + d + 0];
    o.y = scsh[d + 1] * v.y + scsh[D + d + 1];
    o.z = scsh[d + 2] * v.z + scsh[D + d + 2];
    o.w = scsh[d + 3] * v.w + scsh[D + d + 3];
    if (!last) {
        o.x = fmaxf(o.x, 0.f); o.y = fmaxf(o.y, 0.f);
        o.z = fmaxf(o.z, 0.f); o.w = fmaxf(o.w, 0.f);
        ushort4 p;
        p.x = f2b(o.x); p.y = f2b(o.y); p.z = f2b(o.z); p.w = f2b(o.w);
        *(ushort4*)(hb_out + base) = p;
    } else {
        *(float4*)(out_f + base) = o;
    }
}

// ---------------- host launcher ----------------

extern "C" void kernel_launch(void* const* d_in, const int* in_sizes, int n_in,
                              void* d_out, int out_size, void* d_ws, size_t ws_size,
                              hipStream_t stream) {
    const float* x    = (const float*)d_in[0];
    const int*   ei   = (const int*)d_in[1];
    const float* attr = (const float*)d_in[2];
    const float* W1   = (const float*)d_in[3];
    const float* W2   = (const float*)d_in[4];
    const float* Wm   = (const float*)d_in[5];
    const float* bm   = (const float*)d_in[6];
    const float* gam  = (const float*)d_in[7];
    const float* bet  = (const float*)d_in[8];
    float* out = (float*)d_out;

    const int N = in_sizes[0] / D;
    const int E = in_sizes[1] / 2;
    const int L = in_sizes[3] / (3 * D);
    const int NB = (N + 255) / 256;

    size_t off = 0;
    auto carve = [&](size_t bytes) {
        void* p = (char*)d_ws + off;
        off += (bytes + 255) & ~(size_t)255;
        return p;
    };
    int*            deg     = (int*)carve((size_t)N * 4);
    float*          dinv    = (float*)carve((size_t)N * 4);
    int*            row_ptr = (int*)carve((size_t)(N + 1) * 4);
    int*            cursor  = (int*)carve((size_t)N * 4);
    int*            bsum    = (int*)carve((size_t)NB * 4);
    int*            boff    = (int*)carve((size_t)NB * 4);
    int2*           csr     = (int2*)carve((size_t)(E + 4) * 8);
    float4*         cvals   = (float4*)carve((size_t)N * 16);
    unsigned short* xb      = (unsigned short*)carve((size_t)N * D * 2);
    unsigned short* hb      = (unsigned short*)carve((size_t)N * D * 2);
    unsigned short* aggb    = (unsigned short*)carve((size_t)N * D * 2);
    unsigned short* Wmb     = (unsigned short*)carve((size_t)L * D * 256 * 2);
    float*          h2      = (float*)carve((size_t)N * D * 4);
    float*          pbuf    = (float*)carve((size_t)2 * D * PB * 4);
    float*          scsh    = (float*)carve((size_t)2 * D * 4);
    (void)ws_size;

    hipMemsetAsync(deg, 0, (size_t)N * 4, stream);

    const int eb = (E + 255) / 256;
    k_deg<<<eb, 256, 0, stream>>>(ei, E, deg);
    k_dinv<<<NB, 256, 0, stream>>>(deg, dinv, N);
    k_bsum<<<NB, 256, 0, stream>>>(deg, bsum, N);
    k_bscan<<<1, 256, 0, stream>>>(bsum, boff, row_ptr, NB, N, E);
    k_scatter<<<NB, 256, 0, stream>>>(deg, boff, row_ptr, cursor, N);
    k_fill<<<eb, 256, 0, stream>>>(ei, cursor, csr, E);
    k_cvals<<<NB, 256, 0, stream>>>(row_ptr, csr, dinv, attr, cvals, N);

    const int xq = N * D / 4;
    k_cvt<<<(xq + 255) / 256, 256, 0, stream>>>(x, xb, xq);
    const int wq = L * D * 256 / 4;
    k_cvt<<<(wq + 255) / 256, 256, 0, stream>>>(Wm, Wmb, wq);

    const int total4 = N * D / 4;
    const int normb = (total4 + 255) / 256;
    const int gemmb = (N + GROWS - 1) / GROWS;
    const int spmmb = (N + 3) / 4;

    for (int l = 0; l < L; ++l) {
        const unsigned short* in = (l == 0) ? xb : hb;
        const float* W1l = W1 + (size_t)l * 3 * D;
        const float* W2l = W2 + (size_t)l * D;
        const unsigned short* Wml = Wmb + (size_t)l * D * 256;
        const float* bml = bm + (size_t)l * D;

        k_spmm<<<spmmb, 256, 0, stream>>>(in, row_ptr, csr, cvals, W1l, W2l, aggb, N);
        k_gemm<<<gemmb, 256, 0, stream>>>(in, aggb, Wml, bml, h2, pbuf, N);
        k_reduce<<<D, 128, 0, stream>>>(pbuf, gam + (size_t)l * D,
                                        bet + (size_t)l * D, scsh, gemmb, N);
        k_norm<<<normb, 256, 0, stream>>>(h2, scsh, hb, out, total4, (l < L - 1) ? 0 : 1);
    }
}

// Round 5
// 427.781 us; speedup vs baseline: 2.5377x; 1.0928x over previous
//
#include <hip/hip_runtime.h>

#define D 128
#define EPSBN 1e-5f
#define PB 800   // padded partial-buffer stride (>= gemm block count 782)

typedef __attribute__((ext_vector_type(8))) short bf16x8;
typedef __attribute__((ext_vector_type(4))) float f32x4;

static __device__ __forceinline__ unsigned short f2b(float f) {
    unsigned u = __float_as_uint(f);
    unsigned r = u + 0x7FFF + ((u >> 16) & 1);   // RNE
    return (unsigned short)(r >> 16);
}
static __device__ __forceinline__ float b2f_lo(unsigned p) { return __uint_as_float(p << 16); }
static __device__ __forceinline__ float b2f_hi(unsigned p) { return __uint_as_float(p & 0xFFFF0000u); }

// ---------------- setup kernels ----------------

// degree count; atomic return value = edge's rank within its column
__global__ void k_deg(const int* __restrict__ ei, int E, int* __restrict__ deg,
                      int* __restrict__ pos) {
    int e = blockIdx.x * 256 + threadIdx.x;
    if (e < E) pos[e] = atomicAdd(&deg[ei[E + e]], 1);
}

__global__ void k_dinv(const int* __restrict__ deg, float* __restrict__ dinv, int N) {
    int v = blockIdx.x * 256 + threadIdx.x;
    if (v < N) {
        int d = deg[v];
        dinv[v] = (d > 0) ? rsqrtf((float)d) : 0.0f;
    }
}

__global__ void k_bsum(const int* __restrict__ deg, int* __restrict__ bsum, int N) {
    __shared__ int sm[256];
    int t = threadIdx.x, v = blockIdx.x * 256 + t;
    sm[t] = (v < N) ? deg[v] : 0;
    __syncthreads();
    for (int off = 128; off > 0; off >>= 1) {
        if (t < off) sm[t] += sm[t + off];
        __syncthreads();
    }
    if (t == 0) bsum[blockIdx.x] = sm[0];
}

__global__ void k_bscan(const int* __restrict__ bsum, int* __restrict__ boff,
                        int* __restrict__ row_ptr, int NB, int N, int E) {
    __shared__ int sm[256];
    int t = threadIdx.x;
    int v = (t < NB) ? bsum[t] : 0;
    sm[t] = v;
    __syncthreads();
    for (int off = 1; off < 256; off <<= 1) {
        int x = (t >= off) ? sm[t - off] : 0;
        __syncthreads();
        sm[t] += x;
        __syncthreads();
    }
    if (t < NB) boff[t] = sm[t] - v;   // exclusive
    if (t == 0) row_ptr[N] = E;
}

__global__ void k_scatter(const int* __restrict__ deg, const int* __restrict__ boff,
                          int* __restrict__ row_ptr, int N) {
    __shared__ int sm[256];
    int t = threadIdx.x, v = blockIdx.x * 256 + t;
    int val = (v < N) ? deg[v] : 0;
    sm[t] = val;
    __syncthreads();
    for (int off = 1; off < 256; off <<= 1) {
        int x = (t >= off) ? sm[t - off] : 0;
        __syncthreads();
        sm[t] += x;
        __syncthreads();
    }
    if (v < N) row_ptr[v] = boff[blockIdx.x] + sm[t] - val;
}

// atomic-free CSR placement using precomputed ranks
__global__ void k_place(const int* __restrict__ ei, const int* __restrict__ row_ptr,
                        const int* __restrict__ pos, int2* __restrict__ csr, int E) {
    int e = blockIdx.x * 256 + threadIdx.x;
    if (e >= E) return;
    int c = ei[E + e];
    csr[row_ptr[c] + pos[e]] = make_int2(ei[e], e);
}

// cvals[v] = sum nm_e * attr[e]; rewrites csr[j] = (src, nm)
__global__ void k_cvals(const int* __restrict__ row_ptr, int2* __restrict__ csr,
                        const float* __restrict__ dinv, const float* __restrict__ attr,
                        float4* __restrict__ cvals, int N) {
    int v = blockIdx.x * 256 + threadIdx.x;
    if (v >= N) return;
    float dv = dinv[v];
    int jb = row_ptr[v], je = row_ptr[v + 1];
    float4 acc = make_float4(0.f, 0.f, 0.f, 0.f);
    for (int j = jb; j < je; ++j) {
        int2 e = csr[j];
        float nm = dinv[e.x] * dv;
        float4 a = *(const float4*)(attr + (size_t)e.y * 4);
        acc.x += nm * a.x; acc.y += nm * a.y;
        acc.z += nm * a.z; acc.w += nm * a.w;
        csr[j] = make_int2(e.x, __float_as_int(nm));
    }
    cvals[v] = acc;
}

__global__ void k_cvt(const float* __restrict__ in, unsigned short* __restrict__ outp, int n4) {
    int i = blockIdx.x * 256 + threadIdx.x;
    if (i >= n4) return;
    float4 v = *(const float4*)(in + (size_t)i * 4);
    ushort4 p;
    p.x = f2b(v.x); p.y = f2b(v.y); p.z = f2b(v.z); p.w = f2b(v.w);
    *(ushort4*)(outp + (size_t)i * 4) = p;
}

// ---------------- per-layer kernels ----------------

// wave per node, 8 edges/iter (2 predicated slots x 4 quarters).
// Input hb is PRE-NORM bf16 h2 when apply=1: h = relu(sc*x + sh) on the fly.
__global__ __launch_bounds__(256) void k_spmm(
        const unsigned short* __restrict__ hb, const int* __restrict__ row_ptr,
        const int2* __restrict__ csr, const float4* __restrict__ cvals,
        const float* __restrict__ W1l, const float* __restrict__ W2l,
        const float* __restrict__ scsh, int apply,
        unsigned short* __restrict__ aggb, int N) {
    int lane = threadIdx.x & 63;
    int v = blockIdx.x * 4 + (threadIdx.x >> 6);
    if (v >= N) return;
    int qw = lane >> 4;
    int l4 = lane & 15;
    int d0 = l4 * 8;
    int jb = row_ptr[v], je = row_ptr[v + 1];

    float a[8];
#pragma unroll
    for (int i = 0; i < 8; ++i) a[i] = 0.f;

    if (apply) {
        float sc[8], sh[8];
#pragma unroll
        for (int i = 0; i < 8; i += 4) {
            float4 s = *(const float4*)(scsh + d0 + i);
            float4 t = *(const float4*)(scsh + D + d0 + i);
            sc[i] = s.x; sc[i + 1] = s.y; sc[i + 2] = s.z; sc[i + 3] = s.w;
            sh[i] = t.x; sh[i + 1] = t.y; sh[i + 2] = t.z; sh[i + 3] = t.w;
        }
        for (int j0 = jb; j0 < je; j0 += 8) {
            int ja = j0 + qw, jc = j0 + 4 + qw;
            bool oa = (ja < je), oc = (jc < je);
            int2 ea = csr[oa ? ja : jb];
            int2 ec = csr[oc ? jc : jb];
            float na = oa ? __int_as_float(ea.y) : 0.f;
            float nc = oc ? __int_as_float(ec.y) : 0.f;
            uint4 pa = *(const uint4*)(hb + (size_t)ea.x * D + d0);
            uint4 pc = *(const uint4*)(hb + (size_t)ec.x * D + d0);
            float xa[8] = {b2f_lo(pa.x), b2f_hi(pa.x), b2f_lo(pa.y), b2f_hi(pa.y),
                           b2f_lo(pa.z), b2f_hi(pa.z), b2f_lo(pa.w), b2f_hi(pa.w)};
            float xc[8] = {b2f_lo(pc.x), b2f_hi(pc.x), b2f_lo(pc.y), b2f_hi(pc.y),
                           b2f_lo(pc.z), b2f_hi(pc.z), b2f_lo(pc.w), b2f_hi(pc.w)};
#pragma unroll
            for (int i = 0; i < 8; ++i) {
                a[i] += na * fmaxf(sc[i] * xa[i] + sh[i], 0.f);
                a[i] += nc * fmaxf(sc[i] * xc[i] + sh[i], 0.f);
            }
        }
    } else {
        for (int j0 = jb; j0 < je; j0 += 8) {
            int ja = j0 + qw, jc = j0 + 4 + qw;
            bool oa = (ja < je), oc = (jc < je);
            int2 ea = csr[oa ? ja : jb];
            int2 ec = csr[oc ? jc : jb];
            float na = oa ? __int_as_float(ea.y) : 0.f;
            float nc = oc ? __int_as_float(ec.y) : 0.f;
            uint4 pa = *(const uint4*)(hb + (size_t)ea.x * D + d0);
            uint4 pc = *(const uint4*)(hb + (size_t)ec.x * D + d0);
            a[0] += na * b2f_lo(pa.x) + nc * b2f_lo(pc.x);
            a[1] += na * b2f_hi(pa.x) + nc * b2f_hi(pc.x);
            a[2] += na * b2f_lo(pa.y) + nc * b2f_lo(pc.y);
            a[3] += na * b2f_hi(pa.y) + nc * b2f_hi(pc.y);
            a[4] += na * b2f_lo(pa.z) + nc * b2f_lo(pc.z);
            a[5] += na * b2f_hi(pa.z) + nc * b2f_hi(pc.z);
            a[6] += na * b2f_lo(pa.w) + nc * b2f_lo(pc.w);
            a[7] += na * b2f_hi(pa.w) + nc * b2f_hi(pc.w);
        }
    }
#pragma unroll
    for (int i = 0; i < 8; ++i) {
        a[i] += __shfl_xor(a[i], 16);
        a[i] += __shfl_xor(a[i], 32);
    }
    if (qw == 0) {
        float4 c = cvals[v];
        float4 wa0 = *(const float4*)(W1l + d0);
        float4 wa1 = *(const float4*)(W1l + d0 + 4);
        float4 wb0 = *(const float4*)(W1l + D + d0);
        float4 wb1 = *(const float4*)(W1l + D + d0 + 4);
        float4 wc0 = *(const float4*)(W1l + 2 * D + d0);
        float4 wc1 = *(const float4*)(W1l + 2 * D + d0 + 4);
        float4 wd0 = *(const float4*)(W2l + d0);
        float4 wd1 = *(const float4*)(W2l + d0 + 4);
        a[0] += c.x * wa0.x + c.y * wb0.x + c.z * wc0.x + c.w * wd0.x;
        a[1] += c.x * wa0.y + c.y * wb0.y + c.z * wc0.y + c.w * wd0.y;
        a[2] += c.x * wa0.z + c.y * wb0.z + c.z * wc0.z + c.w * wd0.z;
        a[3] += c.x * wa0.w + c.y * wb0.w + c.z * wc0.w + c.w * wd0.w;
        a[4] += c.x * wa1.x + c.y * wb1.x + c.z * wc1.x + c.w * wd1.x;
        a[5] += c.x * wa1.y + c.y * wb1.y + c.z * wc1.y + c.w * wd1.y;
        a[6] += c.x * wa1.z + c.y * wb1.z + c.z * wc1.z + c.w * wd1.z;
        a[7] += c.x * wa1.w + c.y * wb1.w + c.z * wc1.w + c.w * wd1.w;
        uint4 o;
        o.x = ((unsigned)f2b(a[1]) << 16) | (unsigned)f2b(a[0]);
        o.y = ((unsigned)f2b(a[3]) << 16) | (unsigned)f2b(a[2]);
        o.z = ((unsigned)f2b(a[5]) << 16) | (unsigned)f2b(a[4]);
        o.w = ((unsigned)f2b(a[7]) << 16) | (unsigned)f2b(a[6]);
        *(uint4*)(aggb + (size_t)v * D + d0) = o;
    }
}

// h2 = relu([h, agg] @ Wmb^T + bm); h from pre-norm bf16 via on-the-fly affine.
// Output: bf16 pre-norm h2 (hidden layers) or fp32 h2 (last layer).
// Fused per-column sum/sumsq partials -> pbuf.
#define GROWS 64
#define GBK 64
__global__ __launch_bounds__(256) void k_gemm(
        const unsigned short* __restrict__ hsrc, const unsigned short* __restrict__ aggb,
        const unsigned short* __restrict__ Wmb, const float* __restrict__ bml,
        const float* __restrict__ scsh, int applyA,
        unsigned short* __restrict__ h2b, float* __restrict__ h2f, int lastf,
        float* __restrict__ pbuf, int N) {
    __shared__ unsigned short As[GROWS][GBK + 8];
    __shared__ unsigned short Bs[D][GBK + 8];
    __shared__ float sred[2][4][D];
    int tid = threadIdx.x;
    int lane = tid & 63, wave = tid >> 6;
    int n0 = blockIdx.x * GROWS;
    int l15 = lane & 15, q = lane >> 4;
    f32x4 acc[8];
#pragma unroll
    for (int t = 0; t < 8; ++t) acc[t] = (f32x4){0.f, 0.f, 0.f, 0.f};

    for (int kc = 0; kc < 4; ++kc) {
        const unsigned short* src = (kc < 2) ? hsrc : aggb;
        bool aff = (kc < 2) && applyA;
        int k0 = (kc & 1) * GBK;
#pragma unroll
        for (int i = 0; i < 2; ++i) {
            int idx = tid + i * 256;
            int r = idx >> 3, seg = idx & 7;
            uint4 val = make_uint4(0u, 0u, 0u, 0u);
            if (n0 + r < N) val = *(const uint4*)(src + (size_t)(n0 + r) * D + k0 + seg * 8);
            if (aff) {
                int db = k0 + seg * 8;
                float4 s0 = *(const float4*)(scsh + db);
                float4 s1 = *(const float4*)(scsh + db + 4);
                float4 t0 = *(const float4*)(scsh + D + db);
                float4 t1 = *(const float4*)(scsh + D + db + 4);
                float e0 = fmaxf(s0.x * b2f_lo(val.x) + t0.x, 0.f);
                float e1 = fmaxf(s0.y * b2f_hi(val.x) + t0.y, 0.f);
                float e2 = fmaxf(s0.z * b2f_lo(val.y) + t0.z, 0.f);
                float e3 = fmaxf(s0.w * b2f_hi(val.y) + t0.w, 0.f);
                float e4 = fmaxf(s1.x * b2f_lo(val.z) + t1.x, 0.f);
                float e5 = fmaxf(s1.y * b2f_hi(val.z) + t1.y, 0.f);
                float e6 = fmaxf(s1.z * b2f_lo(val.w) + t1.z, 0.f);
                float e7 = fmaxf(s1.w * b2f_hi(val.w) + t1.w, 0.f);
                val.x = ((unsigned)f2b(e1) << 16) | (unsigned)f2b(e0);
                val.y = ((unsigned)f2b(e3) << 16) | (unsigned)f2b(e2);
                val.z = ((unsigned)f2b(e5) << 16) | (unsigned)f2b(e4);
                val.w = ((unsigned)f2b(e7) << 16) | (unsigned)f2b(e6);
            }
            *(uint4*)&As[r][seg * 8] = val;
        }
#pragma unroll
        for (int i = 0; i < 4; ++i) {
            int idx = tid + i * 256;
            int n = idx >> 3, seg = idx & 7;
            *(uint4*)&Bs[n][seg * 8] =
                *(const uint4*)(Wmb + (size_t)n * 256 + kc * GBK + seg * 8);
        }
        __syncthreads();
#pragma unroll
        for (int s = 0; s < 2; ++s) {
            bf16x8 a = *(const bf16x8*)&As[wave * 16 + l15][s * 32 + q * 8];
#pragma unroll
            for (int t = 0; t < 8; ++t) {
                bf16x8 b = *(const bf16x8*)&Bs[t * 16 + l15][s * 32 + q * 8];
                acc[t] = __builtin_amdgcn_mfma_f32_16x16x32_bf16(a, b, acc[t], 0, 0, 0);
            }
        }
        __syncthreads();
    }
    bool full = (n0 + GROWS <= N);
    float ps[8], pq[8];
#pragma unroll
    for (int t = 0; t < 8; ++t) {
        int n = t * 16 + l15;
        float bias = bml[n];
        float s = 0.f, qs = 0.f;
#pragma unroll
        for (int r = 0; r < 4; ++r) {
            int m = n0 + wave * 16 + q * 4 + r;
            float v = fmaxf(acc[t][r] + bias, 0.f);
            if (full || m < N) {
                if (lastf) h2f[(size_t)m * D + n] = v;
                else       h2b[(size_t)m * D + n] = f2b(v);
                s += v; qs += v * v;
            }
        }
        ps[t] = s; pq[t] = qs;
    }
#pragma unroll
    for (int t = 0; t < 8; ++t) {
        ps[t] += __shfl_xor(ps[t], 16); ps[t] += __shfl_xor(ps[t], 32);
        pq[t] += __shfl_xor(pq[t], 16); pq[t] += __shfl_xor(pq[t], 32);
    }
    if (q == 0) {
#pragma unroll
        for (int t = 0; t < 8; ++t) {
            sred[0][wave][t * 16 + l15] = ps[t];
            sred[1][wave][t * 16 + l15] = pq[t];
        }
    }
    __syncthreads();
    if (tid < D) {
        float s = sred[0][0][tid] + sred[0][1][tid] + sred[0][2][tid] + sred[0][3][tid];
        pbuf[(size_t)tid * PB + blockIdx.x] = s;
    } else {
        int n = tid - D;
        float qv = sred[1][0][n] + sred[1][1][n] + sred[1][2][n] + sred[1][3][n];
        pbuf[(size_t)(n + D) * PB + blockIdx.x] = qv;
    }
}

// fold pbuf partials -> scale/shift
__global__ __launch_bounds__(128) void k_reduce(
        const float* __restrict__ pbuf, const float* __restrict__ gam,
        const float* __restrict__ bet, float* __restrict__ scsh, int nb, int N) {
    int n = blockIdx.x;
    int t = threadIdx.x;
    float s = 0.f, qv = 0.f;
    for (int b = t; b < nb; b += 128) {
        s  += pbuf[(size_t)n * PB + b];
        qv += pbuf[(size_t)(n + D) * PB + b];
    }
#pragma unroll
    for (int off = 32; off > 0; off >>= 1) {
        s += __shfl_down(s, off);
        qv += __shfl_down(qv, off);
    }
    __shared__ float aux[4];
    if ((t & 63) == 0) { aux[t >> 6] = s; aux[2 + (t >> 6)] = qv; }
    __syncthreads();
    if (t == 0) {
        float S = aux[0] + aux[1], Q = aux[2] + aux[3];
        float mean = S / (float)N;
        float var = fmaxf(Q / (float)N - mean * mean, 0.f);
        float sc = gam[n] * rsqrtf(var + EPSBN);
        scsh[n] = sc;
        scsh[D + n] = bet[n] - mean * sc;
    }
}

// final output: out = sc*h2f + sh (fp32, no relu)
__global__ void k_norm_last(const float* __restrict__ h2f, const float* __restrict__ scsh,
                            float* __restrict__ out_f, int total4) {
    int i = blockIdx.x * 256 + threadIdx.x;
    if (i >= total4) return;
    int base = i * 4;
    int d = base & (D - 1);
    float4 v = *(const float4*)(h2f + base);
    float4 o;
    o.x = scsh[d + 0] * v.x + scsh[D + d + 0];
    o.y = scsh[d + 1] * v.y + scsh[D + d + 1];
    o.z = scsh[d + 2] * v.z + scsh[D + d + 2];
    o.w = scsh[d + 3] * v.w + scsh[D + d + 3];
    *(float4*)(out_f + base) = o;
}

// ---------------- host launcher ----------------

extern "C" void kernel_launch(void* const* d_in, const int* in_sizes, int n_in,
                              void* d_out, int out_size, void* d_ws, size_t ws_size,
                              hipStream_t stream) {
    const float* x    = (const float*)d_in[0];
    const int*   ei   = (const int*)d_in[1];
    const float* attr = (const float*)d_in[2];
    const float* W1   = (const float*)d_in[3];
    const float* W2   = (const float*)d_in[4];
    const float* Wm   = (const float*)d_in[5];
    const float* bm   = (const float*)d_in[6];
    const float* gam  = (const float*)d_in[7];
    const float* bet  = (const float*)d_in[8];
    float* out = (float*)d_out;

    const int N = in_sizes[0] / D;
    const int E = in_sizes[1] / 2;
    const int L = in_sizes[3] / (3 * D);
    const int NB = (N + 255) / 256;

    size_t off = 0;
    auto carve = [&](size_t bytes) {
        void* p = (char*)d_ws + off;
        off += (bytes + 255) & ~(size_t)255;
        return p;
    };
    int*            deg     = (int*)carve((size_t)N * 4);
    float*          dinv    = (float*)carve((size_t)N * 4);
    int*            row_ptr = (int*)carve((size_t)(N + 1) * 4);
    int*            pos     = (int*)carve((size_t)E * 4);
    int*            bsum    = (int*)carve((size_t)NB * 4);
    int*            boff    = (int*)carve((size_t)NB * 4);
    int2*           csr     = (int2*)carve((size_t)(E + 8) * 8);
    float4*         cvals   = (float4*)carve((size_t)N * 16);
    unsigned short* xb      = (unsigned short*)carve((size_t)N * D * 2);
    unsigned short* h2b     = (unsigned short*)carve((size_t)N * D * 2);
    unsigned short* aggb    = (unsigned short*)carve((size_t)N * D * 2);
    unsigned short* Wmb     = (unsigned short*)carve((size_t)L * D * 256 * 2);
    float*          h2f     = (float*)carve((size_t)N * D * 4);
    float*          pbuf    = (float*)carve((size_t)2 * D * PB * 4);
    float*          scsh    = (float*)carve((size_t)2 * D * 4);
    (void)ws_size;

    hipMemsetAsync(deg, 0, (size_t)N * 4, stream);

    const int eb = (E + 255) / 256;
    k_deg<<<eb, 256, 0, stream>>>(ei, E, deg, pos);
    k_dinv<<<NB, 256, 0, stream>>>(deg, dinv, N);
    k_bsum<<<NB, 256, 0, stream>>>(deg, bsum, N);
    k_bscan<<<1, 256, 0, stream>>>(bsum, boff, row_ptr, NB, N, E);
    k_scatter<<<NB, 256, 0, stream>>>(deg, boff, row_ptr, N);
    k_place<<<eb, 256, 0, stream>>>(ei, row_ptr, pos, csr, E);
    k_cvals<<<NB, 256, 0, stream>>>(row_ptr, csr, dinv, attr, cvals, N);

    const int xq = N * D / 4;
    k_cvt<<<(xq + 255) / 256, 256, 0, stream>>>(x, xb, xq);
    const int wq = L * D * 256 / 4;
    k_cvt<<<(wq + 255) / 256, 256, 0, stream>>>(Wm, Wmb, wq);

    const int total4 = N * D / 4;
    const int gemmb = (N + GROWS - 1) / GROWS;
    const int spmmb = (N + 3) / 4;

    for (int l = 0; l < L; ++l) {
        const unsigned short* in = (l == 0) ? xb : h2b;
        const int apply = (l > 0) ? 1 : 0;
        const int last = (l == L - 1) ? 1 : 0;
        const float* W1l = W1 + (size_t)l * 3 * D;
        const float* W2l = W2 + (size_t)l * D;
        const unsigned short* Wml = Wmb + (size_t)l * D * 256;
        const float* bml = bm + (size_t)l * D;

        k_spmm<<<spmmb, 256, 0, stream>>>(in, row_ptr, csr, cvals, W1l, W2l,
                                          scsh, apply, aggb, N);
        k_gemm<<<gemmb, 256, 0, stream>>>(in, aggb, Wml, bml, scsh, apply,
                                          h2b, h2f, last, pbuf, N);
        k_reduce<<<D, 128, 0, stream>>>(pbuf, gam + (size_t)l * D,
                                        bet + (size_t)l * D, scsh, gemmb, N);
    }
    k_norm_last<<<(total4 + 255) / 256, 256, 0, stream>>>(h2f, scsh, out, total4);
}